// Round 2
// baseline (255.868 us; speedup 1.0000x reference)
//
#include <hip/hip_runtime.h>
#include <math.h>

#define T_TOK 16384   // 4*4096 tokens
#define NEXP  64

// Workspace layout (floats):
//   ws[0..63]   : expert load sums
//   ws[64]      : sum of z^2
//   ws[128 ..]  : w_t transposed gate weights [1024][64]
//
// d_out layout (floats, out_size = 65537):
//   [0, 32768)      top-2 renormalized scores [token][2]
//   [32768, 65536)  top-2 expert indices as floats [token][2]
//   [65536]         total_loss

// ---------------------------------------------------------------------------
// prep: tiled transpose gate_w [64][1024] -> w_t [1024][64]; zero accumulators.
// 16 blocks x 256 threads; both global sides coalesced via LDS 64x65 tile.
// ---------------------------------------------------------------------------
__global__ void moe_prep(const float* __restrict__ gw, float* __restrict__ ws) {
    __shared__ float tile[64][65];
    const int b = blockIdx.x;            // k-range [b*64, b*64+64)
    const int tid = threadIdx.x;         // 256
    if (b == 0 && tid < 128) ws[tid] = 0.f;
#pragma unroll
    for (int it = 0; it < 16; ++it) {
        int idx = it * 256 + tid;        // 0..4095
        int e = idx >> 6, kk = idx & 63;
        tile[e][kk] = gw[e * 1024 + b * 64 + kk];   // coalesced 256B runs
    }
    __syncthreads();
#pragma unroll
    for (int it = 0; it < 16; ++it) {
        int idx = it * 256 + tid;
        int kk = idx >> 6, e = idx & 63;
        ws[128 + (b * 64 + kk) * 64 + e] = tile[e][kk];  // fully coalesced
    }
}

// ---------------------------------------------------------------------------
// main: block = 512 threads = 8 waves = expert-group g(4) x K-half h(2).
// lane = token. w rows wave-uniform -> scalar loads. x staged to LDS with
// XOR-swizzled 16B chunks, double-buffered (one barrier per 64-k step).
// Named prefetch registers (p0..p3) — NO arrays that can spill.
// ---------------------------------------------------------------------------
__launch_bounds__(512)
__global__ void moe_main(const float* __restrict__ x,
                         const float* __restrict__ wt,     // [1024][64]
                         float* __restrict__ acc_ws,
                         float* __restrict__ out) {
    __shared__ float xbuf[2][2][4096];   // [buf][half][row*64 + swz col], 64 KiB
    __shared__ float sc[64][65];         // logits -> exp scores
    __shared__ float c_v1[8][64], c_i1[8][64], c_v2[8][64], c_i2[8][64];
    __shared__ float psum[8][64];
    __shared__ float row_max[64];
    __shared__ float row_inv[64];
    __shared__ float colpart[8][64];

    const int tid  = threadIdx.x;
    const int lane = tid & 63;
    const int wv   = tid >> 6;
    const int g = __builtin_amdgcn_readfirstlane(wv & 3);   // expert group
    const int h = __builtin_amdgcn_readfirstlane(wv >> 2);  // K half
    const int tok0 = blockIdx.x << 6;

    // staging geometry: this thread stages 4 chunks, rows rr0+{0,4,8,12},
    // k-chunk cg, K-tile = wv>>2 (uniform). Global offsets differ by a
    // CONSTANT (+4 rows = +4096 floats) -> one base pointer, no pointer array.
    const int tile = wv >> 2;
    const int rr0  = ((wv & 3) << 4) + (lane >> 4);
    const int cg   = lane & 15;
    const float* gbase = x + (((size_t)(tok0 + rr0)) << 10) + (tile << 9) + (cg << 2);
    const int lo0 = (tile << 12) + ((rr0 +  0) << 6) + ((cg ^ ((rr0 +  0) & 15)) << 2);
    const int lo1 = (tile << 12) + ((rr0 +  4) << 6) + ((cg ^ ((rr0 +  4) & 15)) << 2);
    const int lo2 = (tile << 12) + ((rr0 +  8) << 6) + ((cg ^ ((rr0 +  8) & 15)) << 2);
    const int lo3 = (tile << 12) + ((rr0 + 12) << 6) + ((cg ^ ((rr0 + 12) & 15)) << 2);
    float* xb = &xbuf[0][0][0];

    float acc[16];
#pragma unroll
    for (int e = 0; e < 16; ++e) acc[e] = 0.f;

    // prologue: stage s=0 into buffer 0
    float4 p0 = *(const float4*)(gbase);
    float4 p1 = *(const float4*)(gbase + 4096);
    float4 p2 = *(const float4*)(gbase + 8192);
    float4 p3 = *(const float4*)(gbase + 12288);
    *(float4*)(xb + lo0) = p0;
    *(float4*)(xb + lo1) = p1;
    *(float4*)(xb + lo2) = p2;
    *(float4*)(xb + lo3) = p3;

    const int swz = cg;
    const float* xrow_base = &xbuf[0][h][lane << 6];

#pragma unroll 1
    for (int s = 0; s < 8; ++s) {
        __syncthreads();                         // buf (s&1) ready; buf (s&1)^1 free
        if (s < 7) {                             // issue next-step global loads early
            const float* gs = gbase + ((s + 1) << 6);
            p0 = *(const float4*)(gs);
            p1 = *(const float4*)(gs + 4096);
            p2 = *(const float4*)(gs + 8192);
            p3 = *(const float4*)(gs + 12288);
        }
        const float* xrow = xrow_base + ((s & 1) << 13);
        const float* wrow = wt + (((h << 9) + (s << 6)) << 6) + (g << 4);
#pragma unroll
        for (int c = 0; c < 16; ++c) {
            float4 xv = *(const float4*)(xrow + ((c ^ swz) << 2));
            const float* w0 = wrow + ((c << 2) << 6);
#pragma unroll
            for (int e = 0; e < 16; ++e) acc[e] = fmaf(xv.x, w0[e],       acc[e]);
#pragma unroll
            for (int e = 0; e < 16; ++e) acc[e] = fmaf(xv.y, w0[64 + e],  acc[e]);
#pragma unroll
            for (int e = 0; e < 16; ++e) acc[e] = fmaf(xv.z, w0[128 + e], acc[e]);
#pragma unroll
            for (int e = 0; e < 16; ++e) acc[e] = fmaf(xv.w, w0[192 + e], acc[e]);
        }
        if (s < 7) {                             // stage into the other buffer
            float* xd = xb + ((~s & 1) << 13);
            *(float4*)(xd + lo0) = p0;
            *(float4*)(xd + lo1) = p1;
            *(float4*)(xd + lo2) = p2;
            *(float4*)(xd + lo3) = p3;
        }
    }

    // ---- combine K halves into sc[token][expert]
    if (h == 0) {
#pragma unroll
        for (int e = 0; e < 16; ++e) sc[lane][(g << 4) + e] = acc[e];
    }
    __syncthreads();
    if (h == 1) {
#pragma unroll
        for (int e = 0; e < 16; ++e) sc[lane][(g << 4) + e] += acc[e];
    }
    __syncthreads();

    // ---- epilogue, 8 threads per token ----
    // E1: partial top-2 over 8-expert group
    {
        int t = tid >> 3, sub = tid & 7;
        float v1 = -1e30f, v2 = -1e30f; int i1 = 0, i2 = 0;
#pragma unroll
        for (int j = 0; j < 8; ++j) {
            int e = sub * 8 + j;
            float l = sc[t][e];
            if (l > v1)      { v2 = v1; i2 = i1; v1 = l; i1 = e; }
            else if (l > v2) { v2 = l; i2 = e; }
        }
        c_v1[sub][t] = v1; c_i1[sub][t] = (float)i1;
        c_v2[sub][t] = v2; c_i2[sub][t] = (float)i2;
    }
    __syncthreads();
    // E2: serial merge of 8 candidates (ascending expert order -> tie = lowest idx)
    float tv1 = -1e30f, tv2 = -1e30f; int ti1 = 0, ti2 = 0;
    if (tid < 64) {
        int t = tid;
#pragma unroll
        for (int sub = 0; sub < 8; ++sub) {
            float a1 = c_v1[sub][t]; int a1i = (int)c_i1[sub][t];
            float a2 = c_v2[sub][t]; int a2i = (int)c_i2[sub][t];
            if (a1 > tv1) {
                tv2 = tv1; ti2 = ti1; tv1 = a1; ti1 = a1i;
                if (a2 > tv2) { tv2 = a2; ti2 = a2i; }
            } else if (a1 > tv2) { tv2 = a1; ti2 = a1i; }
        }
        row_max[t] = tv1;
    }
    __syncthreads();
    // E3: exp + partial sums
    {
        int t = tid >> 3, sub = tid & 7;
        float m = row_max[t];
        float ssum = 0.f;
#pragma unroll
        for (int j = 0; j < 8; ++j) {
            int e = sub * 8 + j;
            float ev = expf(sc[t][e] - m);
            sc[t][e] = ev;
            ssum += ev;
        }
        psum[sub][t] = ssum;
    }
    __syncthreads();
    // E4: finalize per token (wave 0 exactly)
    if (tid < 64) {
        int t = tid;
        float ssum = 0.f;
#pragma unroll
        for (int sub = 0; sub < 8; ++sub) ssum += psum[sub][t];
        float inv = 1.f / ssum;
        row_inv[t] = inv;
        float z = row_max[t] + logf(ssum);
        float zsq = z * z;
#pragma unroll
        for (int off = 32; off > 0; off >>= 1) zsq += __shfl_down(zsq, off);
        if (lane == 0) atomicAdd(acc_ws + 64, zsq);

        float p1s = inv;                         // exp(tv1 - m) == 1
        float p2s = expf(tv2 - tv1) * inv;
        float bb  = expf(p2s - p1s);
        float s1 = 1.f / (1.f + bb);
        float s2 = bb * s1;
        int tk = tok0 + t;
        out[2 * tk]     = s1;
        out[2 * tk + 1] = s2;
        out[2 * T_TOK + 2 * tk]     = (float)ti1;
        out[2 * T_TOK + 2 * tk + 1] = (float)ti2;
    }
    __syncthreads();

    // ---- expert-load column sums
    {
        int e  = tid & 63;
        int rg = tid >> 6;
        float sum = 0.f;
#pragma unroll
        for (int r2 = 0; r2 < 8; ++r2) {
            int row = (rg << 3) + r2;
            sum += sc[row][e] * row_inv[row];
        }
        colpart[rg][e] = sum;
    }
    __syncthreads();
    if (tid < 64) {
        float tot = 0.f;
#pragma unroll
        for (int rg = 0; rg < 8; ++rg) tot += colpart[rg][tid];
        atomicAdd(acc_ws + tid, tot);
    }
}

// ---------------------------------------------------------------------------
// finalize: lb_loss + z_loss -> out[65536]. One wave.
// ---------------------------------------------------------------------------
__global__ void moe_finalize(const float* __restrict__ acc_ws,
                             float* __restrict__ out) {
    int e = threadIdx.x;
    float load = acc_ws[e] * (1.f / 16384.f);
    float d = load - (1.f / 64.f);
    float v = d * d;
#pragma unroll
    for (int off = 32; off > 0; off >>= 1) v += __shfl_down(v, off);
    if (e == 0) {
        float lb = 0.01f * 64.f * v;
        float zl = 1e-4f * acc_ws[64] * (1.f / 16384.f);
        out[4 * T_TOK] = lb + zl;
    }
}

extern "C" void kernel_launch(void* const* d_in, const int* in_sizes, int n_in,
                              void* d_out, int out_size, void* d_ws, size_t ws_size,
                              hipStream_t stream) {
    const float* x  = (const float*)d_in[0];   // [4,4096,1024] fp32
    const float* gw = (const float*)d_in[1];   // [64,1024] fp32
    float* out = (float*)d_out;                // 65537 fp32
    float* ws  = (float*)d_ws;

    moe_prep<<<16, 256, 0, stream>>>(gw, ws);
    moe_main<<<256, 512, 0, stream>>>(x, ws + 128, ws, out);
    moe_finalize<<<1, 64, 0, stream>>>(ws, out);
}

// Round 3
// 255.674 us; speedup vs baseline: 1.0008x; 1.0008x over previous
//
#include <hip/hip_runtime.h>
#include <math.h>

#define T_TOK 16384   // 4*4096 tokens
#define NEXP  64

// Workspace layout (floats):
//   ws[0..63]   : expert load sums
//   ws[64]      : sum of z^2
//   ws[128 ..]  : w_t transposed gate weights [1024][64]
//
// d_out layout (floats, out_size = 65537):
//   [0, 32768)      top-2 renormalized scores [token][2]
//   [32768, 65536)  top-2 expert indices as floats [token][2]
//   [65536]         total_loss

// ---------------------------------------------------------------------------
// prep: tiled transpose gate_w [64][1024] -> w_t [1024][64]; zero accumulators.
// ---------------------------------------------------------------------------
__global__ void moe_prep(const float* __restrict__ gw, float* __restrict__ ws) {
    __shared__ float tile[64][65];
    const int b = blockIdx.x;            // k-range [b*64, b*64+64)
    const int tid = threadIdx.x;         // 256
    if (b == 0 && tid < 128) ws[tid] = 0.f;
#pragma unroll
    for (int it = 0; it < 16; ++it) {
        int idx = it * 256 + tid;
        int e = idx >> 6, kk = idx & 63;
        tile[e][kk] = gw[e * 1024 + b * 64 + kk];
    }
    __syncthreads();
#pragma unroll
    for (int it = 0; it < 16; ++it) {
        int idx = it * 256 + tid;
        int kk = idx >> 6, e = idx & 63;
        ws[128 + (b * 64 + kk) * 64 + e] = tile[e][kk];
    }
}

// ---------------------------------------------------------------------------
// main: block = 512 threads = 8 waves = expert-group g(4) x half-step h(2).
// lane = token (64 tokens/block). Steps of 64 k; wave (g,h) computes its
// 16 experts over the h-th 32-k half of each staged tile. w rows are
// wave-uniform -> scalar loads. x double-buffered in LDS, XOR-swizzled,
// ONE barrier per step. Two named float4 prefetch regs — nothing to spill.
// ---------------------------------------------------------------------------
__launch_bounds__(512, 2)
__global__ void moe_main(const float* __restrict__ x,
                         const float* __restrict__ wt,     // [1024][64]
                         float* __restrict__ acc_ws,
                         float* __restrict__ out) {
    __shared__ float xbuf[2][4096];      // 32 KiB: [buf][row*64 + swz chunk]
    __shared__ float sc[64][65];         // logits
    __shared__ float c_v1[8][64], c_i1[8][64], c_v2[8][64], c_i2[8][64];
    __shared__ float psum[8][64];
    __shared__ float row_max[64];
    __shared__ float row_inv[64];
    __shared__ float colpart[8][64];

    const int tid  = threadIdx.x;
    const int lane = tid & 63;
    const int wv   = tid >> 6;
    const int g = __builtin_amdgcn_readfirstlane(wv & 3);   // expert group
    const int h = __builtin_amdgcn_readfirstlane(wv >> 2);  // 32-k half of step
    const int tok0 = blockIdx.x << 6;

    // staging: 1024 chunks/step (64 rows x 16), 2 per thread at rows r, r+32.
    // (r+32)&15 == r&15  ->  second LDS offset = first + 2048. Global offset
    // of the pair differs by a constant 32*1024 floats.
    const int row = tid >> 4;            // 0..31
    const int cg  = tid & 15;
    const float* gbase = x + (((size_t)(tok0 + row)) << 10) + (cg << 2);
    const int lo = (row << 6) + ((cg ^ (row & 15)) << 2);

    float acc[16];
#pragma unroll
    for (int e = 0; e < 16; ++e) acc[e] = 0.f;

    // prologue: stage step 0 into buffer 0
    float4 p0 = *(const float4*)(gbase);
    float4 p1 = *(const float4*)(gbase + 32768);
    *(float4*)(&xbuf[0][0] + lo)        = p0;
    *(float4*)(&xbuf[0][0] + lo + 2048) = p1;

    const int swz = lane & 15;

#pragma unroll 1
    for (int s = 0; s < 16; ++s) {
        __syncthreads();                 // buf s&1 ready; buf (s&1)^1 free
        if (s < 15) {                    // issue next step's global loads early
            const float* gs = gbase + ((s + 1) << 6);
            p0 = *(const float4*)(gs);
            p1 = *(const float4*)(gs + 32768);
        }
        const float* xrow = &xbuf[s & 1][lane << 6];
        const float* wrow = wt + (((s << 6) + (h << 5)) << 6) + (g << 4);
#pragma unroll
        for (int c = 0; c < 8; ++c) {    // 8 chunks = 32 k for this half
            int cc = (h << 3) + c;
            float4 xv = *(const float4*)(xrow + ((cc ^ swz) << 2));
            float xa[4] = {xv.x, xv.y, xv.z, xv.w};
#pragma unroll
            for (int j = 0; j < 4; ++j) {
                const float* wkj = wrow + (((c << 2) + j) << 6);  // uniform
                float xj = xa[j];
#pragma unroll
                for (int e = 0; e < 16; ++e)
                    acc[e] = fmaf(xj, wkj[e], acc[e]);
            }
        }
        if (s < 15) {                    // stage into the other buffer
            float* xd = &xbuf[(s & 1) ^ 1][0];
            *(float4*)(xd + lo)        = p0;
            *(float4*)(xd + lo + 2048) = p1;
        }
    }

    // ---- combine half-step pairs into sc[token][expert]
    if (h == 0) {
#pragma unroll
        for (int e = 0; e < 16; ++e) sc[lane][(g << 4) + e] = acc[e];
    }
    __syncthreads();
    if (h == 1) {
#pragma unroll
        for (int e = 0; e < 16; ++e) sc[lane][(g << 4) + e] += acc[e];
    }
    __syncthreads();

    // ---- epilogue, 8 threads per token ----
    {
        int t = tid >> 3, sub = tid & 7;
        float v1 = -1e30f, v2 = -1e30f; int i1 = 0, i2 = 0;
#pragma unroll
        for (int j = 0; j < 8; ++j) {
            int e = sub * 8 + j;
            float l = sc[t][e];
            if (l > v1)      { v2 = v1; i2 = i1; v1 = l; i1 = e; }
            else if (l > v2) { v2 = l; i2 = e; }
        }
        c_v1[sub][t] = v1; c_i1[sub][t] = (float)i1;
        c_v2[sub][t] = v2; c_i2[sub][t] = (float)i2;
    }
    __syncthreads();
    float tv1 = -1e30f, tv2 = -1e30f; int ti1 = 0, ti2 = 0;
    if (tid < 64) {
        int t = tid;
#pragma unroll
        for (int sub = 0; sub < 8; ++sub) {
            float a1 = c_v1[sub][t]; int a1i = (int)c_i1[sub][t];
            float a2 = c_v2[sub][t]; int a2i = (int)c_i2[sub][t];
            if (a1 > tv1) {
                tv2 = tv1; ti2 = ti1; tv1 = a1; ti1 = a1i;
                if (a2 > tv2) { tv2 = a2; ti2 = a2i; }
            } else if (a1 > tv2) { tv2 = a1; ti2 = a1i; }
        }
        row_max[t] = tv1;
    }
    __syncthreads();
    {
        int t = tid >> 3, sub = tid & 7;
        float m = row_max[t];
        float ssum = 0.f;
#pragma unroll
        for (int j = 0; j < 8; ++j) {
            int e = sub * 8 + j;
            float ev = expf(sc[t][e] - m);
            sc[t][e] = ev;
            ssum += ev;
        }
        psum[sub][t] = ssum;
    }
    __syncthreads();
    if (tid < 64) {
        int t = tid;
        float ssum = 0.f;
#pragma unroll
        for (int sub = 0; sub < 8; ++sub) ssum += psum[sub][t];
        float inv = 1.f / ssum;
        row_inv[t] = inv;
        float z = row_max[t] + logf(ssum);
        float zsq = z * z;
#pragma unroll
        for (int off = 32; off > 0; off >>= 1) zsq += __shfl_down(zsq, off);
        if (lane == 0) atomicAdd(acc_ws + 64, zsq);

        float p1s = inv;                         // exp(tv1 - m) == 1
        float p2s = expf(tv2 - tv1) * inv;
        float bb  = expf(p2s - p1s);
        float s1 = 1.f / (1.f + bb);
        float s2 = bb * s1;
        int tk = tok0 + t;
        out[2 * tk]     = s1;
        out[2 * tk + 1] = s2;
        out[2 * T_TOK + 2 * tk]     = (float)ti1;
        out[2 * T_TOK + 2 * tk + 1] = (float)ti2;
    }
    __syncthreads();

    // ---- expert-load column sums
    {
        int e  = tid & 63;
        int rg = tid >> 6;
        float sum = 0.f;
#pragma unroll
        for (int r2 = 0; r2 < 8; ++r2) {
            int r = (rg << 3) + r2;
            sum += sc[r][e] * row_inv[r];
        }
        colpart[rg][e] = sum;
    }
    __syncthreads();
    if (tid < 64) {
        float tot = 0.f;
#pragma unroll
        for (int rg = 0; rg < 8; ++rg) tot += colpart[rg][tid];
        atomicAdd(acc_ws + tid, tot);
    }
}

// ---------------------------------------------------------------------------
// finalize: lb_loss + z_loss -> out[65536]. One wave.
// ---------------------------------------------------------------------------
__global__ void moe_finalize(const float* __restrict__ acc_ws,
                             float* __restrict__ out) {
    int e = threadIdx.x;
    float load = acc_ws[e] * (1.f / 16384.f);
    float d = load - (1.f / 64.f);
    float v = d * d;
#pragma unroll
    for (int off = 32; off > 0; off >>= 1) v += __shfl_down(v, off);
    if (e == 0) {
        float lb = 0.01f * 64.f * v;
        float zl = 1e-4f * acc_ws[64] * (1.f / 16384.f);
        out[4 * T_TOK] = lb + zl;
    }
}

extern "C" void kernel_launch(void* const* d_in, const int* in_sizes, int n_in,
                              void* d_out, int out_size, void* d_ws, size_t ws_size,
                              hipStream_t stream) {
    const float* x  = (const float*)d_in[0];   // [4,4096,1024] fp32
    const float* gw = (const float*)d_in[1];   // [64,1024] fp32
    float* out = (float*)d_out;                // 65537 fp32
    float* ws  = (float*)d_ws;

    moe_prep<<<16, 256, 0, stream>>>(gw, ws);
    moe_main<<<256, 512, 0, stream>>>(x, ws + 128, ws, out);
    moe_finalize<<<1, 64, 0, stream>>>(ws, out);
}

// Round 4
// 145.966 us; speedup vs baseline: 1.7529x; 1.7516x over previous
//
#include <hip/hip_runtime.h>
#include <math.h>

#define T_TOK 16384   // 4*4096 tokens
#define NEXP  64

// Workspace layout (floats):
//   ws[0..63]   : expert load sums
//   ws[64]      : sum of z^2
//   ws[66]      : block-done counter (int)
//   ws[128 ..]  : w_t transposed gate weights [1024][64]
//
// d_out layout (floats, out_size = 65537):
//   [0, 32768)      top-2 renormalized scores [token][2]
//   [32768, 65536)  top-2 expert indices as floats [token][2]
//   [65536]         total_loss

// ---------------------------------------------------------------------------
// prep: tiled transpose gate_w [64][1024] -> w_t [1024][64]; zero accumulators
// (including the done-counter at ws[66]).
// ---------------------------------------------------------------------------
__global__ void moe_prep(const float* __restrict__ gw, float* __restrict__ ws) {
    __shared__ float tile[64][65];
    const int b = blockIdx.x;            // k-range [b*64, b*64+64)
    const int tid = threadIdx.x;         // 256
    if (b == 0 && tid < 128) ws[tid] = 0.f;
#pragma unroll
    for (int it = 0; it < 16; ++it) {
        int idx = it * 256 + tid;
        int e = idx >> 6, kk = idx & 63;
        tile[e][kk] = gw[e * 1024 + b * 64 + kk];
    }
    __syncthreads();
#pragma unroll
    for (int it = 0; it < 16; ++it) {
        int idx = it * 256 + tid;
        int kk = idx >> 6, e = idx & 63;
        ws[128 + (b * 64 + kk) * 64 + e] = tile[e][kk];
    }
}

// ---------------------------------------------------------------------------
// main: EXACT round-1 structure (proven pure-FMA codegen: VALU time == FMA
// floor), with the spilled arrays replaced by named registers and
// __launch_bounds__(512,2) so the allocator has room (round-1 spilled at
// VGPR=40). block = 512 = 8 waves = expert-group g(4) x K-half h(2);
// lane = token. w rows wave-uniform -> scalar loads. x staged via LDS,
// XOR-swizzled 16B chunks, two barriers per 64-k step.
// ---------------------------------------------------------------------------
__launch_bounds__(512, 2)
__global__ void moe_main(const float* __restrict__ x,
                         const float* __restrict__ wt,     // [1024][64]
                         float* __restrict__ acc_ws,
                         float* __restrict__ out) {
    __shared__ float xbuf[2][4096];      // [K-half][row*64 + swz chunk], 32 KiB
    __shared__ float sc[64][65];         // logits -> exp scores
    __shared__ float row_inv[64];
    __shared__ float colpart[8][64];
    __shared__ int   is_last;

    const int tid  = threadIdx.x;
    const int lane = tid & 63;
    const int wv   = tid >> 6;
    const int g = __builtin_amdgcn_readfirstlane(wv & 3);   // expert group
    const int h = __builtin_amdgcn_readfirstlane(wv >> 2);  // K half
    const int tok0 = blockIdx.x << 6;

    // staging: 2048 chunks/step, 4 per thread at rows rr0+{0,4,8,12} of
    // K-tile (wv>>2). Global addresses differ by constant +4 rows -> one
    // base pointer + named offsets; LDS offsets are 4 named ints.
    const int tile = wv >> 2;
    const int rr0  = ((wv & 3) << 4) + (lane >> 4);
    const int cg   = lane & 15;
    const float* gbase = x + (((size_t)(tok0 + rr0)) << 10) + (tile << 9) + (cg << 2);
    const int lo0 = (tile << 12) + ((rr0 +  0) << 6) + ((cg ^ ((rr0 +  0) & 15)) << 2);
    const int lo1 = (tile << 12) + ((rr0 +  4) << 6) + ((cg ^ ((rr0 +  4) & 15)) << 2);
    const int lo2 = (tile << 12) + ((rr0 +  8) << 6) + ((cg ^ ((rr0 +  8) & 15)) << 2);
    const int lo3 = (tile << 12) + ((rr0 + 12) << 6) + ((cg ^ ((rr0 + 12) & 15)) << 2);
    float* xb = &xbuf[0][0];

    float acc[16];
#pragma unroll
    for (int e = 0; e < 16; ++e) acc[e] = 0.f;

    // prologue prefetch of step 0 (named regs -- nothing to spill)
    float4 p0 = *(const float4*)(gbase);
    float4 p1 = *(const float4*)(gbase + 4096);
    float4 p2 = *(const float4*)(gbase + 8192);
    float4 p3 = *(const float4*)(gbase + 12288);

    const int swz = cg;
    const float* xrow = &xbuf[h][lane << 6];

#pragma unroll 1
    for (int s = 0; s < 8; ++s) {
        __syncthreads();                                  // xbuf free
        *(float4*)(xb + lo0) = p0;
        *(float4*)(xb + lo1) = p1;
        *(float4*)(xb + lo2) = p2;
        *(float4*)(xb + lo3) = p3;
        __syncthreads();                                  // xbuf ready
        if (s < 7) {                                      // prefetch next step
            const float* gs = gbase + ((s + 1) << 6);
            p0 = *(const float4*)(gs);
            p1 = *(const float4*)(gs + 4096);
            p2 = *(const float4*)(gs + 8192);
            p3 = *(const float4*)(gs + 12288);
        }
        // k = h*512 + s*64 + c*4 + j
        const float* wrow = wt + (((h << 9) + (s << 6)) << 6) + (g << 4);
#pragma unroll
        for (int c = 0; c < 16; ++c) {
            float4 xv = *(const float4*)(xrow + ((c ^ swz) << 2));
            float xa[4] = {xv.x, xv.y, xv.z, xv.w};
#pragma unroll
            for (int j = 0; j < 4; ++j) {
                const float* wkj = wrow + (((c << 2) + j) << 6);  // uniform -> s_load
                float xj = xa[j];
#pragma unroll
                for (int e = 0; e < 16; ++e)
                    acc[e] = fmaf(xj, wkj[e], acc[e]);
            }
        }
    }

    // ---- combine K halves into sc[token][expert]
    if (h == 0) {
#pragma unroll
        for (int e = 0; e < 16; ++e) sc[lane][(g << 4) + e] = acc[e];
    }
    __syncthreads();
    if (h == 1) {
#pragma unroll
        for (int e = 0; e < 16; ++e) sc[lane][(g << 4) + e] += acc[e];
    }
    __syncthreads();

    // ---- per-token epilogue (round-1 serial version: 0 bank conflicts)
    if (tid < 64) {
        const int r = tid;
        float v1 = -1e30f, v2 = -1e30f;
        int i1 = 0, i2 = 0;
        for (int j = 0; j < 64; ++j) {          // top-2 scan; ties -> lower index
            float l = sc[r][j];
            if (l > v1)      { v2 = v1; i2 = i1; v1 = l; i1 = j; }
            else if (l > v2) { v2 = l; i2 = j; }
        }
        float m = v1;                           // max logit
        float ssum = 0.f;
        for (int j = 0; j < 64; ++j) {
            float ev = expf(sc[r][j] - m);
            ssum += ev;
            sc[r][j] = ev;
        }
        float inv = 1.f / ssum;
        row_inv[r] = inv;
        float z = m + logf(ssum);               // logsumexp
        float zsq = z * z;
#pragma unroll
        for (int off = 32; off > 0; off >>= 1) zsq += __shfl_down(zsq, off);
        if (lane == 0) atomicAdd(acc_ws + 64, zsq);

        float p1s = inv;                        // exp(v1-m) == 1
        float p2s = expf(v2 - m) * inv;
        float bb  = expf(p2s - p1s);
        float s1 = 1.f / (1.f + bb);
        float s2 = bb * s1;
        int t = tok0 + r;
        out[2 * t]     = s1;
        out[2 * t + 1] = s2;
        out[2 * T_TOK + 2 * t]     = (float)i1;
        out[2 * T_TOK + 2 * t + 1] = (float)i2;
    }
    __syncthreads();

    // ---- expert load column sums
    {
        int e  = tid & 63;
        int rg = tid >> 6;
        float sum = 0.f;
#pragma unroll
        for (int r2 = 0; r2 < 8; ++r2) {
            int row = (rg << 3) + r2;
            sum += sc[row][e] * row_inv[row];
        }
        colpart[rg][e] = sum;
    }
    __syncthreads();
    if (tid < 64) {
        float tot = 0.f;
#pragma unroll
        for (int rg = 0; rg < 8; ++rg) tot += colpart[rg][tid];
        atomicAdd(acc_ws + tid, tot);           // device-scope
    }

    // ---- last-block finalize (replaces the moe_finalize launch)
    __syncthreads();                            // all this block's atomics issued
    if (tid == 0) {
        __threadfence();                        // release our atomic adds
        int old = __hip_atomic_fetch_add((int*)(acc_ws + 66), 1,
                                         __ATOMIC_ACQ_REL, __HIP_MEMORY_SCOPE_AGENT);
        is_last = (old == 255) ? 1 : 0;
    }
    __syncthreads();
    if (is_last && tid < 64) {
        __threadfence();                        // acquire side
        float load = __hip_atomic_load(acc_ws + tid, __ATOMIC_RELAXED,
                                       __HIP_MEMORY_SCOPE_AGENT) * (1.f / 16384.f);
        float d = load - (1.f / 64.f);
        float v = d * d;
#pragma unroll
        for (int off = 32; off > 0; off >>= 1) v += __shfl_down(v, off);
        if (tid == 0) {
            float zsum = __hip_atomic_load(acc_ws + 64, __ATOMIC_RELAXED,
                                           __HIP_MEMORY_SCOPE_AGENT);
            float lb = 0.01f * 64.f * v;
            float zl = 1e-4f * zsum * (1.f / 16384.f);
            out[4 * T_TOK] = lb + zl;           // index 65536
        }
    }
}

extern "C" void kernel_launch(void* const* d_in, const int* in_sizes, int n_in,
                              void* d_out, int out_size, void* d_ws, size_t ws_size,
                              hipStream_t stream) {
    const float* x  = (const float*)d_in[0];   // [4,4096,1024] fp32
    const float* gw = (const float*)d_in[1];   // [64,1024] fp32
    float* out = (float*)d_out;                // 65537 fp32
    float* ws  = (float*)d_ws;

    moe_prep<<<16, 256, 0, stream>>>(gw, ws);
    moe_main<<<256, 512, 0, stream>>>(x, ws + 128, ws, out);
}

// Round 5
// 144.897 us; speedup vs baseline: 1.7659x; 1.0074x over previous
//
#include <hip/hip_runtime.h>
#include <math.h>

#define T_TOK 16384   // 4*4096 tokens
#define NEXP  64

// Workspace layout (floats):
//   ws[0..63]   : expert load sums
//   ws[64]      : sum of z^2
//   ws[66]      : block-done counter (int)
//   ws[128 ..]  : w_t transposed gate weights [1024][64]
//
// d_out layout (floats, out_size = 65537):
//   [0, 32768)      top-2 renormalized scores [token][2]
//   [32768, 65536)  top-2 expert indices as floats [token][2]
//   [65536]         total_loss

// ---------------------------------------------------------------------------
// prep: tiled transpose gate_w [64][1024] -> w_t [1024][64]; zero accumulators
// ---------------------------------------------------------------------------
__global__ void moe_prep(const float* __restrict__ gw, float* __restrict__ ws) {
    __shared__ float tile[64][65];
    const int b = blockIdx.x;
    const int tid = threadIdx.x;         // 256
    if (b == 0 && tid < 128) ws[tid] = 0.f;
#pragma unroll
    for (int it = 0; it < 16; ++it) {
        int idx = it * 256 + tid;
        int e = idx >> 6, kk = idx & 63;
        tile[e][kk] = gw[e * 1024 + b * 64 + kk];
    }
    __syncthreads();
#pragma unroll
    for (int it = 0; it < 16; ++it) {
        int idx = it * 256 + tid;
        int kk = idx >> 6, e = idx & 63;
        ws[128 + (b * 64 + kk) * 64 + e] = tile[e][kk];
    }
}

// ---------------------------------------------------------------------------
// main: round-4 structure (clean pure-FMA codegen) with the K-loop step body
// reorganized so the x ds_reads are a single up-front burst into 16 named
// float4 regs. The FMA region's lgkmcnt then tracks ONLY the w s_loads ->
// precise scalar waits, deep s_load pipelining. sched_barrier(0) pins the
// burst so the scheduler cannot re-interleave ds_reads with s_loads.
// ---------------------------------------------------------------------------
#define LOADX(cc) float4 xv##cc = *(const float4*)(xrow + (((cc) ^ swz) << 2));

#define CBLOCK(cc) do {                                                        \
    float xa0 = xv##cc.x, xa1 = xv##cc.y, xa2 = xv##cc.z, xa3 = xv##cc.w;      \
    const float* wk = wrow + ((cc) << 8);                                      \
    _Pragma("unroll")                                                          \
    for (int j = 0; j < 4; ++j) {                                              \
        float xj = j == 0 ? xa0 : j == 1 ? xa1 : j == 2 ? xa2 : xa3;           \
        const float* wkj = wk + (j << 6);   /* wave-uniform -> s_load */       \
        _Pragma("unroll")                                                      \
        for (int e = 0; e < 16; ++e)                                           \
            acc[e] = fmaf(xj, wkj[e], acc[e]);                                 \
    }                                                                          \
} while (0)

__launch_bounds__(512, 2)
__global__ void moe_main(const float* __restrict__ x,
                         const float* __restrict__ wt,     // [1024][64]
                         float* __restrict__ acc_ws,
                         float* __restrict__ out) {
    __shared__ float xbuf[2][4096];      // [K-half][row*64 + swz chunk], 32 KiB
    __shared__ float sc[64][65];         // logits -> exp scores
    __shared__ float row_inv[64];
    __shared__ float colpart[8][64];
    __shared__ int   is_last;

    const int tid  = threadIdx.x;
    const int lane = tid & 63;
    const int wv   = tid >> 6;
    const int g = __builtin_amdgcn_readfirstlane(wv & 3);   // expert group
    const int h = __builtin_amdgcn_readfirstlane(wv >> 2);  // K half
    const int tok0 = blockIdx.x << 6;

    // staging: 2048 chunks/step, 4 per thread at rows rr0+{0,4,8,12} of
    // K-tile (wv>>2); one base pointer + named offsets.
    const int tile = wv >> 2;
    const int rr0  = ((wv & 3) << 4) + (lane >> 4);
    const int cg   = lane & 15;
    const float* gbase = x + (((size_t)(tok0 + rr0)) << 10) + (tile << 9) + (cg << 2);
    const int lo0 = (tile << 12) + ((rr0 +  0) << 6) + ((cg ^ ((rr0 +  0) & 15)) << 2);
    const int lo1 = (tile << 12) + ((rr0 +  4) << 6) + ((cg ^ ((rr0 +  4) & 15)) << 2);
    const int lo2 = (tile << 12) + ((rr0 +  8) << 6) + ((cg ^ ((rr0 +  8) & 15)) << 2);
    const int lo3 = (tile << 12) + ((rr0 + 12) << 6) + ((cg ^ ((rr0 + 12) & 15)) << 2);
    float* xb = &xbuf[0][0];

    float acc[16];
#pragma unroll
    for (int e = 0; e < 16; ++e) acc[e] = 0.f;

    // prologue prefetch of step 0
    float4 p0 = *(const float4*)(gbase);
    float4 p1 = *(const float4*)(gbase + 4096);
    float4 p2 = *(const float4*)(gbase + 8192);
    float4 p3 = *(const float4*)(gbase + 12288);

    const int swz = cg;
    const float* xrow = &xbuf[h][lane << 6];

#pragma unroll 1
    for (int s = 0; s < 8; ++s) {
        __syncthreads();                                  // xbuf free
        *(float4*)(xb + lo0) = p0;
        *(float4*)(xb + lo1) = p1;
        *(float4*)(xb + lo2) = p2;
        *(float4*)(xb + lo3) = p3;
        __syncthreads();                                  // xbuf ready
        if (s < 7) {                                      // global prefetch (vmcnt)
            const float* gs = gbase + ((s + 1) << 6);
            p0 = *(const float4*)(gs);
            p1 = *(const float4*)(gs + 4096);
            p2 = *(const float4*)(gs + 8192);
            p3 = *(const float4*)(gs + 12288);
        }
        // x burst: 16 ds_read_b128 into named regs, drained once
        LOADX(0)  LOADX(1)  LOADX(2)  LOADX(3)
        LOADX(4)  LOADX(5)  LOADX(6)  LOADX(7)
        LOADX(8)  LOADX(9)  LOADX(10) LOADX(11)
        LOADX(12) LOADX(13) LOADX(14) LOADX(15)
        __builtin_amdgcn_sched_barrier(0);                // pin the burst
        // k = h*512 + s*64 + c*4 + j ; FMA region sees only s_loads on lgkm
        const float* wrow = wt + (((h << 9) + (s << 6)) << 6) + (g << 4);
        CBLOCK(0);  CBLOCK(1);  CBLOCK(2);  CBLOCK(3);
        CBLOCK(4);  CBLOCK(5);  CBLOCK(6);  CBLOCK(7);
        CBLOCK(8);  CBLOCK(9);  CBLOCK(10); CBLOCK(11);
        CBLOCK(12); CBLOCK(13); CBLOCK(14); CBLOCK(15);
    }

    // ---- combine K halves into sc[token][expert]
    if (h == 0) {
#pragma unroll
        for (int e = 0; e < 16; ++e) sc[lane][(g << 4) + e] = acc[e];
    }
    __syncthreads();
    if (h == 1) {
#pragma unroll
        for (int e = 0; e < 16; ++e) sc[lane][(g << 4) + e] += acc[e];
    }
    __syncthreads();

    // ---- per-token epilogue (serial, 0 bank conflicts, proven absmax 0)
    if (tid < 64) {
        const int r = tid;
        float v1 = -1e30f, v2 = -1e30f;
        int i1 = 0, i2 = 0;
        for (int j = 0; j < 64; ++j) {
            float l = sc[r][j];
            if (l > v1)      { v2 = v1; i2 = i1; v1 = l; i1 = j; }
            else if (l > v2) { v2 = l; i2 = j; }
        }
        float m = v1;
        float ssum = 0.f;
        for (int j = 0; j < 64; ++j) {
            float ev = expf(sc[r][j] - m);
            ssum += ev;
            sc[r][j] = ev;
        }
        float inv = 1.f / ssum;
        row_inv[r] = inv;
        float z = m + logf(ssum);
        float zsq = z * z;
#pragma unroll
        for (int off = 32; off > 0; off >>= 1) zsq += __shfl_down(zsq, off);
        if (lane == 0) atomicAdd(acc_ws + 64, zsq);

        float p1s = inv;                        // exp(v1-m) == 1
        float p2s = expf(v2 - m) * inv;
        float bb  = expf(p2s - p1s);
        float s1 = 1.f / (1.f + bb);
        float s2 = bb * s1;
        int t = tok0 + r;
        out[2 * t]     = s1;
        out[2 * t + 1] = s2;
        out[2 * T_TOK + 2 * t]     = (float)i1;
        out[2 * T_TOK + 2 * t + 1] = (float)i2;
    }
    __syncthreads();

    // ---- expert load column sums
    {
        int e  = tid & 63;
        int rg = tid >> 6;
        float sum = 0.f;
#pragma unroll
        for (int r2 = 0; r2 < 8; ++r2) {
            int row = (rg << 3) + r2;
            sum += sc[row][e] * row_inv[row];
        }
        colpart[rg][e] = sum;
    }
    __syncthreads();
    if (tid < 64) {
        float tot = 0.f;
#pragma unroll
        for (int rg = 0; rg < 8; ++rg) tot += colpart[rg][tid];
        atomicAdd(acc_ws + tid, tot);           // device-scope
    }

    // ---- last-block finalize
    __syncthreads();
    if (tid == 0) {
        __threadfence();
        int old = __hip_atomic_fetch_add((int*)(acc_ws + 66), 1,
                                         __ATOMIC_ACQ_REL, __HIP_MEMORY_SCOPE_AGENT);
        is_last = (old == 255) ? 1 : 0;
    }
    __syncthreads();
    if (is_last && tid < 64) {
        __threadfence();
        float load = __hip_atomic_load(acc_ws + tid, __ATOMIC_RELAXED,
                                       __HIP_MEMORY_SCOPE_AGENT) * (1.f / 16384.f);
        float d = load - (1.f / 64.f);
        float v = d * d;
#pragma unroll
        for (int off = 32; off > 0; off >>= 1) v += __shfl_down(v, off);
        if (tid == 0) {
            float zsum = __hip_atomic_load(acc_ws + 64, __ATOMIC_RELAXED,
                                           __HIP_MEMORY_SCOPE_AGENT);
            float lb = 0.01f * 64.f * v;
            float zl = 1e-4f * zsum * (1.f / 16384.f);
            out[4 * T_TOK] = lb + zl;
        }
    }
}

extern "C" void kernel_launch(void* const* d_in, const int* in_sizes, int n_in,
                              void* d_out, int out_size, void* d_ws, size_t ws_size,
                              hipStream_t stream) {
    const float* x  = (const float*)d_in[0];   // [4,4096,1024] fp32
    const float* gw = (const float*)d_in[1];   // [64,1024] fp32
    float* out = (float*)d_out;                // 65537 fp32
    float* ws  = (float*)d_ws;

    moe_prep<<<16, 256, 0, stream>>>(gw, ws);
    moe_main<<<256, 512, 0, stream>>>(x, ws + 128, ws, out);
}